// Round 1
// 431.942 us; speedup vs baseline: 1.0386x; 1.0386x over previous
//
#include <hip/hip_runtime.h>
#include <hip/hip_fp16.h>

// SSIM, B=16, C=1, H=W=1024, 11x11 separable Gaussian (sigma=20 -> near-flat).
// v2: LDS halved via fp16 intermediates -> 4 blocks/CU (was 2, LDS-capped).
//   phase 1: horizontal blur img -> S (half, 84x74)
//   phase 2 (fused): vertical blur -> mu; d = img - mu (global re-read, L2-hot);
//            fused min/max; store d as half into D1/D2. No fp32 mu buffer.
//   phase 3/4 (x3 stats): product+H-blur -> HP (half, in S region), V-blur ->
//            per-thread register stats.
//   combine: mu reconstructed as img - d (third read, L2-hot); 1st-order Taylor
//            in (C1,C2) -> three C-independent sums.
// All arithmetic fp32; fp16 only as LDS storage (round-to-nearest-even).
// Error budget ~3e-4/pixel random-sign, mean over 16.7M px -> ~1e-4 final.

#define IMG_H 1024
#define IMG_W 1024
#define TS    64          // output tile
#define MW    74          // TS + 10 (d region)
#define DST   80          // D1/D2 stride in halves (160 B, 16B-aligned rows)
#define HR    84          // TS + 20 (rows for horizontal pass)
#define HSTH  80          // S stride in halves (160 B)
#define HPW   64          // HP stride in halves (128 B)
#define NSTRIP 19         // ceil(74/4) column strips in phase 1

__device__ __forceinline__ unsigned fkey(float f) {
  unsigned b = __float_as_uint(f);
  return (b & 0x80000000u) ? ~b : (b | 0x80000000u);
}
__device__ __forceinline__ float funkey(unsigned k) {
  return (k & 0x80000000u) ? __uint_as_float(k & 0x7FFFFFFFu)
                           : __uint_as_float(~k);
}

__global__ void ssim_init(unsigned* __restrict__ ws) {
  ws[0] = 0u;           // sum S0*B0
  ws[1] = 0u;           // sum S0*B'   (C1 coefficient)
  ws[2] = 0u;           // sum B0*S'   (C2 coefficient)
  ws[3] = 0xFFFFFFFFu;  // min key
  ws[4] = 0u;           // max key
}

// one statistic: fused (product + horizontal blur) -> HP (half), then vertical
// blur into dst registers. SIDX: 0 = d1*d1, 1 = d2*d2, 2 = d1*d2.
template <int SIDX>
__device__ __forceinline__ void stat_pass(int tid, const float g[11],
                                          __half* __restrict__ HP,
                                          const __half* __restrict__ DA,
                                          const __half* __restrict__ DB,
                                          int R0o, int c_own, float dst[16]) {
  for (unsigned idx = tid; idx < MW * 16u; idx += 256) {
    unsigned i = idx >> 4;
    int oc0 = (int)(idx & 15u) * 4;
    const __half* rA = &DA[i * DST + oc0];
    const __half* rB = &DB[i * DST + oc0];
    float p[16];
    #pragma unroll
    for (int t = 0; t < 4; ++t) {
      float a0 = 0.f, a1 = 0.f, a2 = 0.f, a3 = 0.f;
      float b0 = 0.f, b1 = 0.f, b2 = 0.f, b3 = 0.f;
      if (SIDX != 1) {
        uint2 u = *(const uint2*)(rA + 4 * t);   // 8B-aligned: oc0 mult 4 halves
        __half2 h0 = *(__half2*)&u.x, h1 = *(__half2*)&u.y;
        a0 = __half2float(h0.x); a1 = __half2float(h0.y);
        a2 = __half2float(h1.x); a3 = __half2float(h1.y);
      }
      if (SIDX != 0) {
        uint2 u = *(const uint2*)(rB + 4 * t);
        __half2 h0 = *(__half2*)&u.x, h1 = *(__half2*)&u.y;
        b0 = __half2float(h0.x); b1 = __half2float(h0.y);
        b2 = __half2float(h1.x); b3 = __half2float(h1.y);
      }
      p[4 * t + 0] = (SIDX == 0) ? a0 * a0 : (SIDX == 1) ? b0 * b0 : a0 * b0;
      p[4 * t + 1] = (SIDX == 0) ? a1 * a1 : (SIDX == 1) ? b1 * b1 : a1 * b1;
      p[4 * t + 2] = (SIDX == 0) ? a2 * a2 : (SIDX == 1) ? b2 * b2 : a2 * b2;
      p[4 * t + 3] = (SIDX == 0) ? a3 * a3 : (SIDX == 1) ? b3 * b3 : a3 * b3;
    }
    float oq[4];
    #pragma unroll
    for (int q = 0; q < 4; ++q) {
      float acc = 0.f;
      #pragma unroll
      for (int j = 0; j < 11; ++j) acc = fmaf(g[j], p[q + j], acc);
      oq[q] = acc;
    }
    __half2 h01 = __floats2half2_rn(oq[0], oq[1]);
    __half2 h23 = __floats2half2_rn(oq[2], oq[3]);
    uint2 pk;
    pk.x = *(unsigned*)&h01;
    pk.y = *(unsigned*)&h23;
    *(uint2*)&HP[i * HPW + oc0] = pk;   // byte off = 128*i + 8*m -> 8B aligned
  }
  __syncthreads();
  // vertical blur: thread owns col c_own, rows [R0o, R0o+16)
  float win[26];
  #pragma unroll
  for (int j = 0; j < 26; ++j)
    win[j] = __half2float(HP[(R0o + j) * HPW + c_own]);
  #pragma unroll
  for (int k = 0; k < 16; ++k) {
    float acc = 0.f;
    #pragma unroll
    for (int j = 0; j < 11; ++j) acc = fmaf(g[j], win[k + j], acc);
    dst[k] = acc;
  }
}

__global__ __launch_bounds__(256, 4)
void ssim_main(const float* __restrict__ img1, const float* __restrict__ img2,
               const float* __restrict__ kern, unsigned* __restrict__ ws) {
  __shared__ __align__(16) __half S[HR * HSTH];   // 13440 B: H-blur buf, reused as HP
  __shared__ __align__(16) __half D1[MW * DST];   // 11840 B: d1 (half)
  __shared__ __align__(16) __half D2[MW * DST];   // 11840 B: d2 (half)
  __shared__ float gsh[16];
  __shared__ float redbuf[4][8];
  // total ~37.3 KB -> 4 blocks/CU (was 71 KB -> 2 blocks/CU)

  const int tid = threadIdx.x;
  const int r0 = blockIdx.y * TS;
  const int c0 = blockIdx.x * TS;
  const size_t boff = (size_t)blockIdx.z * (IMG_H * IMG_W);
  const float* i1 = img1 + boff;
  const float* i2 = img2 + boff;

  if (tid < 11) gsh[tid] = kern[55 + tid] * rsqrtf(kern[60]);
  __syncthreads();
  float g[11];
  #pragma unroll
  for (int j = 0; j < 11; ++j) g[j] = gsh[j];

  float vmin = 1e30f, vmax = -1e30f;

  // ---- per image: H-blur -> S(half); fused V-blur + d -> D(half) ----
  #pragma unroll
  for (int im = 0; im < 2; ++im) {
    const float* img = im ? i2 : i1;
    __half* D = im ? D2 : D1;

    // phase 1: horizontal blur into S (half). Zero-padding outside the image.
    for (unsigned idx = tid; idx < HR * NSTRIP; idx += 256) {
      unsigned rr = idx / NSTRIP;
      unsigned strip = idx - rr * NSTRIP;
      int cc0 = (int)strip * 4;
      int gr = r0 - 10 + (int)rr;
      int gcb = c0 + cc0 - 10;
      float w[14];
      if (gr >= 0 && gr < IMG_H) {
        const float* rowp = img + (size_t)gr * IMG_W;
        if (gcb >= 0 && gcb + 14 <= IMG_W) {
          const float2* p2 = (const float2*)(rowp + gcb);  // gcb even -> aligned
          #pragma unroll
          for (int k = 0; k < 7; ++k) {
            float2 t = p2[k];
            w[2 * k] = t.x; w[2 * k + 1] = t.y;
          }
        } else {
          #pragma unroll
          for (int k = 0; k < 14; ++k) {
            int gc = gcb + k;
            w[k] = (gc >= 0 && gc < IMG_W) ? rowp[gc] : 0.f;
          }
        }
      } else {
        #pragma unroll
        for (int k = 0; k < 14; ++k) w[k] = 0.f;
      }
      float oq[4];
      #pragma unroll
      for (int q = 0; q < 4; ++q) {
        float acc = 0.f;
        #pragma unroll
        for (int j = 0; j < 11; ++j) acc = fmaf(g[j], w[q + j], acc);
        oq[q] = acc;
      }
      __half2 h01 = __floats2half2_rn(oq[0], oq[1]);
      __half2 h23 = __floats2half2_rn(oq[2], oq[3]);
      uint2 pk;
      pk.x = *(unsigned*)&h01;
      pk.y = *(unsigned*)&h23;
      *(uint2*)&S[rr * HSTH + cc0] = pk;  // 8B-aligned packed store
    }
    __syncthreads();

    // phase 2 (fused): vertical blur -> mu; d = img - mu (0 outside image);
    // min/max; store d (half). 4 rows x 2 cols per item, 19*37 = 703 items.
    for (unsigned idx = tid; idx < 19u * 37u; idx += 256) {
      unsigned rbv = idx / 37u;
      unsigned cp = idx - rbv * 37u;
      int R0v = (int)rbv * 4;
      int j0 = (int)cp * 2;
      float wa[14], wb[14];
      #pragma unroll
      for (int j = 0; j < 14; ++j) {
        int rr = R0v + j;
        if (rr < HR) {
          __half2 h = *(const __half2*)&S[rr * HSTH + j0];  // j0 even -> 4B align
          wa[j] = __half2float(h.x);
          wb[j] = __half2float(h.y);
        } else { wa[j] = 0.f; wb[j] = 0.f; }
      }
      #pragma unroll
      for (int q = 0; q < 4; ++q) {
        int r2 = R0v + q;
        if (r2 < MW) {
          float mua = 0.f, mub = 0.f;
          #pragma unroll
          for (int j = 0; j < 11; ++j) {
            mua = fmaf(g[j], wa[q + j], mua);
            mub = fmaf(g[j], wb[q + j], mub);
          }
          int gr = r0 - 5 + r2;
          int gc = c0 - 5 + j0;
          float da = 0.f, db = 0.f;
          if (gr >= 0 && gr < IMG_H) {
            const float* rowp = img + (size_t)gr * IMG_W;
            if (gc >= 0 && gc < IMG_W) {
              float v = rowp[gc];
              vmin = fminf(vmin, v); vmax = fmaxf(vmax, v);
              da = v - mua;
            }
            if (gc + 1 >= 0 && gc + 1 < IMG_W) {
              float v = rowp[gc + 1];
              vmin = fminf(vmin, v); vmax = fmaxf(vmax, v);
              db = v - mub;
            }
          }
          // packed half2 store, lanes stride 4B -> conflict-free
          *(__half2*)&D[r2 * DST + j0] = __floats2half2_rn(da, db);
        }
      }
    }
    __syncthreads();
  }

  // thread owns col c_own, rows [R0o, R0o+16) of the 64x64 output tile
  const int c_own = tid & 63;
  const int R0o = (tid >> 6) * 16;

  float s11r[16], s22r[16], s12r[16];
  stat_pass<0>(tid, g, S, D1, D2, R0o, c_own, s11r);
  __syncthreads();
  stat_pass<1>(tid, g, S, D1, D2, R0o, c_own, s22r);
  __syncthreads();
  stat_pass<2>(tid, g, S, D1, D2, R0o, c_own, s12r);

  // combine: mu reconstructed as img - d (L2-hot re-read).
  // ssim ~= S0*B0 + C1*(S0*B') + C2*(B0*S')  (1st-order Taylor)
  const float* p1 = i1 + (size_t)(r0 + R0o) * IMG_W + (c0 + c_own);
  const float* p2 = i2 + (size_t)(r0 + R0o) * IMG_W + (c0 + c_own);
  float acc0 = 0.f, aC1 = 0.f, aC2 = 0.f;
  #pragma unroll
  for (int k = 0; k < 16; ++k) {
    float d1v = __half2float(D1[(R0o + k + 5) * DST + (c_own + 5)]);
    float d2v = __half2float(D2[(R0o + k + 5) * DST + (c_own + 5)]);
    float v1 = p1[(size_t)k * IMG_W];
    float v2 = p2[(size_t)k * IMG_W];
    float m1 = v1 - d1v;                 // mu1 reconstruction
    float m2 = v2 - d2v;
    float s1 = s11r[k] + 1.f;            // sigma1_sq
    float s2 = s22r[k] + 1.f;            // sigma2_sq
    float s12v = s12r[k] + 1.f;          // sigma12
    float a = 2.f * s12v;
    float b = s1 + s2;
    float rb = __builtin_amdgcn_rcpf(b);
    float S0 = a * rb;
    float Sp = (b - a) * rb * rb;        // dS/dC2
    float m12 = fmaf(m1, m2, 1.f);
    float nb = 2.f * m12;
    float N1 = nb * nb;
    float ms = fmaf(m1, m1, fmaf(m2, m2, 2.f));
    float D1v = ms * ms;
    float rD = __builtin_amdgcn_rcpf(D1v);
    float B0 = N1 * rD;
    float Bp = (D1v - N1) * rD * rD;     // dB/dC1
    acc0 = fmaf(S0, B0, acc0);
    aC1 = fmaf(S0, Bp, aC1);
    aC2 = fmaf(B0, Sp, aC2);
  }

  // block reduction: wave shuffle then 4 wave partials via LDS
  #pragma unroll
  for (int off = 32; off > 0; off >>= 1) {
    acc0 += __shfl_down(acc0, off);
    aC1 += __shfl_down(aC1, off);
    aC2 += __shfl_down(aC2, off);
    vmin = fminf(vmin, __shfl_down(vmin, off));
    vmax = fmaxf(vmax, __shfl_down(vmax, off));
  }
  const int wv = tid >> 6, ln = tid & 63;
  if (ln == 0) {
    redbuf[wv][0] = acc0; redbuf[wv][1] = aC1; redbuf[wv][2] = aC2;
    redbuf[wv][3] = vmin; redbuf[wv][4] = vmax;
  }
  __syncthreads();
  if (tid == 0) {
    float t0 = 0.f, t1 = 0.f, t2 = 0.f, mn = 1e30f, mx = -1e30f;
    #pragma unroll
    for (int w2 = 0; w2 < 4; ++w2) {
      t0 += redbuf[w2][0]; t1 += redbuf[w2][1]; t2 += redbuf[w2][2];
      mn = fminf(mn, redbuf[w2][3]); mx = fmaxf(mx, redbuf[w2][4]);
    }
    float* wsF = (float*)ws;
    atomicAdd(&wsF[0], t0);
    atomicAdd(&wsF[1], t1);
    atomicAdd(&wsF[2], t2);
    atomicMin(&ws[3], fkey(mn));
    atomicMax(&ws[4], fkey(mx));
  }
}

__global__ void ssim_final(const unsigned* __restrict__ ws, float* __restrict__ out) {
  const float* wsF = (const float*)ws;
  float mn = funkey(ws[3]);
  float mx = funkey(ws[4]);
  float vr = mx - mn + 1e-5f;
  float c1 = 0.01f * vr; c1 *= c1;
  float c2 = 0.03f * vr; c2 *= c2;
  float mean = (wsF[0] + c1 * wsF[1] + c2 * wsF[2]) * (1.0f / 16777216.0f);
  out[0] = 1.f - mean;
}

extern "C" void kernel_launch(void* const* d_in, const int* in_sizes, int n_in,
                              void* d_out, int out_size, void* d_ws, size_t ws_size,
                              hipStream_t stream) {
  const float* img1 = (const float*)d_in[0];
  const float* img2 = (const float*)d_in[1];
  const float* kern = (const float*)d_in[2];
  unsigned* ws = (unsigned*)d_ws;
  float* out = (float*)d_out;
  (void)in_sizes; (void)n_in; (void)out_size; (void)ws_size;

  hipLaunchKernelGGL(ssim_init, dim3(1), dim3(1), 0, stream, ws);
  hipLaunchKernelGGL(ssim_main, dim3(IMG_W / TS, IMG_H / TS, 16), dim3(256), 0,
                     stream, img1, img2, kern, ws);
  hipLaunchKernelGGL(ssim_final, dim3(1), dim3(1), 0, stream, ws, out);
}

// Round 4
// 370.866 us; speedup vs baseline: 1.2097x; 1.1647x over previous
//
#include <hip/hip_runtime.h>

// SSIM, B=16, C=1, H=W=1024, 11x11 separable Gaussian.
// v3c: barrier-free register-streaming waves (no LDS tiles). Resubmit of v3b
// (two broker-level infra failures, no kernel signal) with launch_bounds
// relaxed (256,4)->(256,2) so the ~77 rolling-window registers can never
// spill to scratch (VGPR cap 256 instead of 128).
//   Each wave owns a 64-lane column strip (44 useful + 10+10 halo) and streams
//   84 image rows of one 64-row band. Vertical state = per-lane rolling
//   11-deep register windows (static indexing via 11x-unrolled inner loop):
//     w1,w2   : raw img rows (V-blur source + d = img - mu reconstruction)
//     m1w,m2w : mu delay (combine needs mu 5 steps after computation)
//     p11/p22/p12 : H-blurred product rows (stats V-blur source)
//   Horizontal exchange via ds_bpermute (full-wave crossbar, 40/row).
//   Pipeline at step t (img row rt = r0-10+t):
//     commit prefetched row t; prefetch t+1
//     Vimg(rt-5) = V-blur(w);  mu(rt-5) = H-blur(Vimg) via bpermute
//     d(rt-5) = img(rt-5) - mu (0 outside image)
//     hp(rt-5) = H-blur of {d1d1,d2d2,d1d2} via bpermute of d
//     t>=20: stats(rt-10) = V-blur(p*); combine with mu(rt-10) (Taylor in C1,C2)
//   All fp32. Zero __syncthreads in hot loop; tiny LDS for final reduce only.

#define IMG_H 1024
#define IMG_W 1024
#define USEC   44                      // useful cols per wave
#define NSTRIP 24                      // 24*44 = 1056 >= 1024
#define BAND   64                      // output rows per wave
#define NBAND  16
#define NBATCH 16
#define NWAVES (NSTRIP * NBAND * NBATCH)   // 6144
#define NBLK   (NWAVES / 4)                // 1536 blocks of 4 waves

__device__ __forceinline__ unsigned fkey(float f) {
  unsigned b = __float_as_uint(f);
  return (b & 0x80000000u) ? ~b : (b | 0x80000000u);
}
__device__ __forceinline__ float funkey(unsigned k) {
  return (k & 0x80000000u) ? __uint_as_float(k & 0x7FFFFFFFu)
                           : __uint_as_float(~k);
}

__device__ __forceinline__ float xlane(float v, int addr) {
  // full-wave (64-lane) register crossbar; addr in bytes, lane = addr[7:2]
  return __int_as_float(__builtin_amdgcn_ds_bpermute(addr, __float_as_int(v)));
}

__global__ void ssim_init(unsigned* __restrict__ ws) {
  ws[0] = 0u;           // sum S0*B0
  ws[1] = 0u;           // sum S0*B'   (C1 coefficient)
  ws[2] = 0u;           // sum B0*S'   (C2 coefficient)
  ws[3] = 0xFFFFFFFFu;  // min key
  ws[4] = 0u;           // max key
}

__global__ __launch_bounds__(256, 2)
void ssim_main(const float* __restrict__ img1, const float* __restrict__ img2,
               const float* __restrict__ kern, unsigned* __restrict__ ws) {
  __shared__ float redbuf[4][8];

  const int tid = threadIdx.x;
  const int lane = tid & 63;
  const int wv = tid >> 6;
  const int wid = blockIdx.x * 4 + wv;

  const int strip = wid % NSTRIP;
  const int rem = wid / NSTRIP;
  const int band = rem % NBAND;
  const int batch = rem / NBAND;

  const size_t boff = (size_t)batch * (IMG_H * IMG_W);
  const float* i1 = img1 + boff;
  const float* i2 = img2 + boff;

  // separable weights: g[j] = k2d[5][j] / sqrt(k2d[5][5])  (uniform -> SGPR)
  float g[11];
  #pragma unroll
  for (int j = 0; j < 11; ++j) g[j] = kern[55 + j] * rsqrtf(kern[60]);

  const int col = strip * USEC + lane - 10;    // absolute column of this lane
  const bool cok = (col >= 0) && (col < IMG_W);
  const int cidx = min(max(col, 0), IMG_W - 1);
  const bool oma = (lane >= 10) && (lane < 54) && (col < IMG_W); // output lane
  const int r0 = band * BAND;
  const int a4 = lane * 4;                     // bpermute self byte-address

  // rolling windows (statically indexed -> registers)
  float w1[11] = {}, w2[11] = {};
  float m1w[11] = {}, m2w[11] = {};
  float p11[11] = {}, p22[11] = {}, p12[11] = {};

  float acc0 = 0.f, aC1 = 0.f, aC2 = 0.f;
  float vmin = 1e30f, vmax = -1e30f;

  // prefetch row for t = 0 (img row r0-10)
  float nv1, nv2;
  {
    int rin = r0 - 10;
    if ((unsigned)rin < IMG_H) {
      nv1 = i1[(size_t)rin * IMG_W + cidx];
      nv2 = i2[(size_t)rin * IMG_W + cidx];
    } else { nv1 = 0.f; nv2 = 0.f; }
  }

  #pragma unroll 1
  for (int m = 0; m < 8; ++m) {
    #pragma unroll
    for (int c = 0; c < 11; ++c) {
      const int t = m * 11 + c;                // step; img row rt = r0-10+t

      // commit prefetched row t (column-masked -> zero padding)
      float v1 = cok ? nv1 : 0.f;
      float v2 = cok ? nv2 : 0.f;
      w1[c] = v1; w2[c] = v2;
      vmin = fminf(vmin, fminf(v1, v2));       // pad zeros: negligible vs true min
      vmax = fmaxf(vmax, fmaxf(v1, v2));

      // prefetch row t+1 (latency hidden under this step's compute)
      if (t < 83) {
        int rin = r0 - 9 + t;
        if ((unsigned)rin < IMG_H) {
          nv1 = i1[(size_t)rin * IMG_W + cidx];
          nv2 = i2[(size_t)rin * IMG_W + cidx];
        } else { nv1 = 0.f; nv2 = 0.f; }
      } else { nv1 = 0.f; nv2 = 0.f; }

      // vertical blur over img rows rt-10..rt -> Vimg at row rt-5
      float V1 = 0.f, V2 = 0.f;
      #pragma unroll
      for (int j = 0; j < 11; ++j) {
        V1 = fmaf(g[j], w1[(c + 1 + j) % 11], V1);
        V2 = fmaf(g[j], w2[(c + 1 + j) % 11], V2);
      }

      // horizontal blur via crossbar -> mu(rt-5); Gaussian is symmetric:
      // g[5-o] == g[5+o] bitwise -> fold left/right taps.
      float mu1 = g[5] * V1, mu2 = g[5] * V2;
      #pragma unroll
      for (int o = 1; o <= 5; ++o) {
        float l1 = xlane(V1, a4 - 4 * o);
        float r1 = xlane(V1, a4 + 4 * o);
        float l2 = xlane(V2, a4 - 4 * o);
        float r2 = xlane(V2, a4 + 4 * o);
        float sg = g[5 + o];
        mu1 = fmaf(sg, l1 + r1, mu1);
        mu2 = fmaf(sg, l2 + r2, mu2);
      }
      m1w[c] = mu1; m2w[c] = mu2;

      // d at row rt-5 (0 outside the image, matching zero-padded second conv)
      const bool drok = ((unsigned)(r0 - 15 + t) < IMG_H);
      float d1 = (drok && cok) ? (w1[(c + 6) % 11] - mu1) : 0.f;
      float d2 = (drok && cok) ? (w2[(c + 6) % 11] - mu2) : 0.f;

      // fused products + horizontal blur via crossbar of d -> hp(rt-5)
      float h11 = (g[5] * d1) * d1;
      float h22 = (g[5] * d2) * d2;
      float h12 = (g[5] * d1) * d2;
      #pragma unroll
      for (int o = 1; o <= 5; ++o) {
        float l1 = xlane(d1, a4 - 4 * o);
        float l2 = xlane(d2, a4 - 4 * o);
        float r1 = xlane(d1, a4 + 4 * o);
        float r2 = xlane(d2, a4 + 4 * o);
        float u = g[5 + o];                    // == g[5 - o]
        h11 = fmaf(u, fmaf(l1, l1, r1 * r1), h11);
        h22 = fmaf(u, fmaf(l2, l2, r2 * r2), h22);
        h12 = fmaf(u, fmaf(l1, l2, r1 * r2), h12);
      }
      p11[c] = h11; p22[c] = h22; p12[c] = h12;

      // output row rt-10 (valid steps 20..83)
      if (t >= 20 && t < 84) {
        float s11 = 0.f, s22 = 0.f, s12 = 0.f;
        #pragma unroll
        for (int j = 0; j < 11; ++j) {
          float gj = g[j];
          s11 = fmaf(gj, p11[(c + 1 + j) % 11], s11);
          s22 = fmaf(gj, p22[(c + 1 + j) % 11], s22);
          s12 = fmaf(gj, p12[(c + 1 + j) % 11], s12);
        }
        float M1 = m1w[(c + 6) % 11], M2 = m2w[(c + 6) % 11];

        float s1 = s11 + 1.f;                  // sigma1_sq
        float s2 = s22 + 1.f;                  // sigma2_sq
        float sv = s12 + 1.f;                  // sigma12
        float a = 2.f * sv;
        float b = s1 + s2;                     // >= 2 on valid lanes
        float rb = __builtin_amdgcn_rcpf(b);
        float S0 = a * rb;
        float Sp = (b - a) * rb * rb;          // dS/dC2
        float m12 = fmaf(M1, M2, 1.f);
        float nb = 2.f * m12;
        float N1 = nb * nb;
        float ms = fmaf(M1, M1, fmaf(M2, M2, 2.f));
        float Dv = ms * ms;                    // >= 4 on valid lanes
        float rD = __builtin_amdgcn_rcpf(Dv);
        float B0 = N1 * rD;
        float Bp = (Dv - N1) * rD * rD;        // dB/dC1
        float t0v = S0 * B0, t1v = S0 * Bp, t2v = B0 * Sp;
        acc0 += oma ? t0v : 0.f;               // select blocks NaN from halo lanes
        aC1 += oma ? t1v : 0.f;
        aC2 += oma ? t2v : 0.f;
      }
    }
  }

  // wave reduction (64 lanes), then block partials via tiny LDS
  #pragma unroll
  for (int off = 32; off > 0; off >>= 1) {
    acc0 += __shfl_down(acc0, off);
    aC1 += __shfl_down(aC1, off);
    aC2 += __shfl_down(aC2, off);
    vmin = fminf(vmin, __shfl_down(vmin, off));
    vmax = fmaxf(vmax, __shfl_down(vmax, off));
  }
  if (lane == 0) {
    redbuf[wv][0] = acc0; redbuf[wv][1] = aC1; redbuf[wv][2] = aC2;
    redbuf[wv][3] = vmin; redbuf[wv][4] = vmax;
  }
  __syncthreads();
  if (tid == 0) {
    float t0 = 0.f, t1 = 0.f, t2 = 0.f, mn = 1e30f, mx = -1e30f;
    #pragma unroll
    for (int w2 = 0; w2 < 4; ++w2) {
      t0 += redbuf[w2][0]; t1 += redbuf[w2][1]; t2 += redbuf[w2][2];
      mn = fminf(mn, redbuf[w2][3]); mx = fmaxf(mx, redbuf[w2][4]);
    }
    float* wsF = (float*)ws;
    atomicAdd(&wsF[0], t0);
    atomicAdd(&wsF[1], t1);
    atomicAdd(&wsF[2], t2);
    atomicMin(&ws[3], fkey(mn));
    atomicMax(&ws[4], fkey(mx));
  }
}

__global__ void ssim_final(const unsigned* __restrict__ ws, float* __restrict__ out) {
  const float* wsF = (const float*)ws;
  float mn = funkey(ws[3]);
  float mx = funkey(ws[4]);
  float vr = mx - mn + 1e-5f;
  float c1 = 0.01f * vr; c1 *= c1;
  float c2 = 0.03f * vr; c2 *= c2;
  float mean = (wsF[0] + c1 * wsF[1] + c2 * wsF[2]) * (1.0f / 16777216.0f);
  out[0] = 1.f - mean;
}

extern "C" void kernel_launch(void* const* d_in, const int* in_sizes, int n_in,
                              void* d_out, int out_size, void* d_ws, size_t ws_size,
                              hipStream_t stream) {
  const float* img1 = (const float*)d_in[0];
  const float* img2 = (const float*)d_in[1];
  const float* kern = (const float*)d_in[2];
  unsigned* ws = (unsigned*)d_ws;
  float* out = (float*)d_out;
  (void)in_sizes; (void)n_in; (void)out_size; (void)ws_size;

  hipLaunchKernelGGL(ssim_init, dim3(1), dim3(1), 0, stream, ws);
  hipLaunchKernelGGL(ssim_main, dim3(NBLK), dim3(256), 0, stream,
                     img1, img2, kern, ws);
  hipLaunchKernelGGL(ssim_final, dim3(1), dim3(1), 0, stream, ws, out);
}

// Round 5
// 319.354 us; speedup vs baseline: 1.4048x; 1.1613x over previous
//
#include <hip/hip_runtime.h>
#include <hip/hip_fp16.h>

// SSIM, B=16, C=1, H=W=1024, 11x11 separable Gaussian.
// v4: register-streaming waves (v3c structure, verified correct) with
// half2-PACKED bpermute exchanges: the two horizontal-blur lane exchanges
// move (V1,V2) and (d1,d2) as one packed half2 word instead of two fp32
// words -> 40 -> 20 ds_bpermute per step. DS pipe was the binder
// (21.6M bpermutes ~ 211 us/CU at ~6cy; VALUBusy only 35%).
// Compute stays fp32; only neighbor taps are half-rounded (center exact).
//   Each wave owns a 64-lane column strip (44 useful + 10+10 halo) and streams
//   84 image rows of one 64-row band. Vertical state = per-lane rolling
//   11-deep register windows (static indexing via 11x-unrolled inner loop):
//     w1,w2   : raw img rows (V-blur source + d = img - mu reconstruction)
//     m1w,m2w : mu delay (combine needs mu 5 steps after computation)
//     p11/p22/p12 : H-blurred product rows (stats V-blur source)
//   Pipeline at step t (img row rt = r0-10+t):
//     commit prefetched row t; prefetch t+1
//     Vimg(rt-5) = V-blur(w);  mu(rt-5) = H-blur(Vimg) via packed bpermute
//     d(rt-5) = img(rt-5) - mu (0 outside image)
//     hp(rt-5) = H-blur of {d1d1,d2d2,d1d2} via packed bpermute of d
//     t>=20: stats(rt-10) = V-blur(p*); combine with mu(rt-10) (Taylor in C1,C2)
//   Zero __syncthreads in hot loop; tiny LDS for final reduce only.

#define IMG_H 1024
#define IMG_W 1024
#define USEC   44                      // useful cols per wave
#define NSTRIP 24                      // 24*44 = 1056 >= 1024
#define BAND   64                      // output rows per wave
#define NBAND  16
#define NBATCH 16
#define NWAVES (NSTRIP * NBAND * NBATCH)   // 6144
#define NBLK   (NWAVES / 4)                // 1536 blocks of 4 waves

__device__ __forceinline__ unsigned fkey(float f) {
  unsigned b = __float_as_uint(f);
  return (b & 0x80000000u) ? ~b : (b | 0x80000000u);
}
__device__ __forceinline__ float funkey(unsigned k) {
  return (k & 0x80000000u) ? __uint_as_float(k & 0x7FFFFFFFu)
                           : __uint_as_float(~k);
}

__device__ __forceinline__ unsigned xlane_u(unsigned v, int addr) {
  // full-wave (64-lane) register crossbar; addr in bytes, lane = addr[7:2]
  return (unsigned)__builtin_amdgcn_ds_bpermute(addr, (int)v);
}

__global__ void ssim_init(unsigned* __restrict__ ws) {
  ws[0] = 0u;           // sum S0*B0
  ws[1] = 0u;           // sum S0*B'   (C1 coefficient)
  ws[2] = 0u;           // sum B0*S'   (C2 coefficient)
  ws[3] = 0xFFFFFFFFu;  // min key
  ws[4] = 0u;           // max key
}

__global__ __launch_bounds__(256, 2)
void ssim_main(const float* __restrict__ img1, const float* __restrict__ img2,
               const float* __restrict__ kern, unsigned* __restrict__ ws) {
  __shared__ float redbuf[4][8];

  const int tid = threadIdx.x;
  const int lane = tid & 63;
  const int wv = tid >> 6;
  const int wid = blockIdx.x * 4 + wv;

  const int strip = wid % NSTRIP;
  const int rem = wid / NSTRIP;
  const int band = rem % NBAND;
  const int batch = rem / NBAND;

  const size_t boff = (size_t)batch * (IMG_H * IMG_W);
  const float* i1 = img1 + boff;
  const float* i2 = img2 + boff;

  // separable weights: g[j] = k2d[5][j] / sqrt(k2d[5][5])  (uniform -> SGPR)
  float g[11];
  #pragma unroll
  for (int j = 0; j < 11; ++j) g[j] = kern[55 + j] * rsqrtf(kern[60]);

  const int col = strip * USEC + lane - 10;    // absolute column of this lane
  const bool cok = (col >= 0) && (col < IMG_W);
  const int cidx = min(max(col, 0), IMG_W - 1);
  const bool oma = (lane >= 10) && (lane < 54) && (col < IMG_W); // output lane
  const int r0 = band * BAND;
  const int a4 = lane * 4;                     // bpermute self byte-address

  // rolling windows (statically indexed -> registers)
  float w1[11] = {}, w2[11] = {};
  float m1w[11] = {}, m2w[11] = {};
  float p11[11] = {}, p22[11] = {}, p12[11] = {};

  float acc0 = 0.f, aC1 = 0.f, aC2 = 0.f;
  float vmin = 1e30f, vmax = -1e30f;

  // prefetch row for t = 0 (img row r0-10)
  float nv1, nv2;
  {
    int rin = r0 - 10;
    if ((unsigned)rin < IMG_H) {
      nv1 = i1[(size_t)rin * IMG_W + cidx];
      nv2 = i2[(size_t)rin * IMG_W + cidx];
    } else { nv1 = 0.f; nv2 = 0.f; }
  }

  #pragma unroll 1
  for (int m = 0; m < 8; ++m) {
    #pragma unroll
    for (int c = 0; c < 11; ++c) {
      const int t = m * 11 + c;                // step; img row rt = r0-10+t

      // commit prefetched row t (column-masked -> zero padding)
      float v1 = cok ? nv1 : 0.f;
      float v2 = cok ? nv2 : 0.f;
      w1[c] = v1; w2[c] = v2;
      vmin = fminf(vmin, fminf(v1, v2));       // pad zeros: negligible vs true min
      vmax = fmaxf(vmax, fmaxf(v1, v2));

      // prefetch row t+1 (latency hidden under this step's compute)
      if (t < 83) {
        int rin = r0 - 9 + t;
        if ((unsigned)rin < IMG_H) {
          nv1 = i1[(size_t)rin * IMG_W + cidx];
          nv2 = i2[(size_t)rin * IMG_W + cidx];
        } else { nv1 = 0.f; nv2 = 0.f; }
      } else { nv1 = 0.f; nv2 = 0.f; }

      // vertical blur over img rows rt-10..rt -> Vimg at row rt-5
      float V1 = 0.f, V2 = 0.f;
      #pragma unroll
      for (int j = 0; j < 11; ++j) {
        V1 = fmaf(g[j], w1[(c + 1 + j) % 11], V1);
        V2 = fmaf(g[j], w2[(c + 1 + j) % 11], V2);
      }

      // horizontal blur via PACKED crossbar -> mu(rt-5).
      // (V1,V2) travel as one half2 word; center tap stays fp32.
      // Gaussian symmetric: g[5-o] == g[5+o] bitwise.
      unsigned pv;
      {
        __half2 pV = __floats2half2_rn(V1, V2);
        pv = *(unsigned*)&pV;
      }
      float mu1 = g[5] * V1, mu2 = g[5] * V2;
      #pragma unroll
      for (int o = 1; o <= 5; ++o) {
        unsigned ul = xlane_u(pv, a4 - 4 * o);
        unsigned ur = xlane_u(pv, a4 + 4 * o);
        __half2 hl = *(__half2*)&ul;
        __half2 hr = *(__half2*)&ur;
        float sg = g[5 + o];
        mu1 = fmaf(sg, __low2float(hl), mu1);
        mu1 = fmaf(sg, __low2float(hr), mu1);
        mu2 = fmaf(sg, __high2float(hl), mu2);
        mu2 = fmaf(sg, __high2float(hr), mu2);
      }
      m1w[c] = mu1; m2w[c] = mu2;

      // d at row rt-5 (0 outside the image, matching zero-padded second conv)
      const bool drok = ((unsigned)(r0 - 15 + t) < IMG_H);
      float d1 = (drok && cok) ? (w1[(c + 6) % 11] - mu1) : 0.f;
      float d2 = (drok && cok) ? (w2[(c + 6) % 11] - mu2) : 0.f;

      // fused products + horizontal blur via PACKED crossbar of (d1,d2)
      unsigned pd;
      {
        __half2 pD = __floats2half2_rn(d1, d2);
        pd = *(unsigned*)&pD;
      }
      float h11 = (g[5] * d1) * d1;
      float h22 = (g[5] * d2) * d2;
      float h12 = (g[5] * d1) * d2;
      #pragma unroll
      for (int o = 1; o <= 5; ++o) {
        unsigned ul = xlane_u(pd, a4 - 4 * o);
        unsigned ur = xlane_u(pd, a4 + 4 * o);
        __half2 hl = *(__half2*)&ul;
        __half2 hr = *(__half2*)&ur;
        float l1 = __low2float(hl), l2 = __high2float(hl);
        float r1 = __low2float(hr), r2 = __high2float(hr);
        float u = g[5 + o];                    // == g[5 - o]
        h11 = fmaf(u, fmaf(l1, l1, r1 * r1), h11);
        h22 = fmaf(u, fmaf(l2, l2, r2 * r2), h22);
        h12 = fmaf(u, fmaf(l1, l2, r1 * r2), h12);
      }
      p11[c] = h11; p22[c] = h22; p12[c] = h12;

      // output row rt-10 (valid steps 20..83)
      if (t >= 20 && t < 84) {
        float s11 = 0.f, s22 = 0.f, s12 = 0.f;
        #pragma unroll
        for (int j = 0; j < 11; ++j) {
          float gj = g[j];
          s11 = fmaf(gj, p11[(c + 1 + j) % 11], s11);
          s22 = fmaf(gj, p22[(c + 1 + j) % 11], s22);
          s12 = fmaf(gj, p12[(c + 1 + j) % 11], s12);
        }
        float M1 = m1w[(c + 6) % 11], M2 = m2w[(c + 6) % 11];

        float s1 = s11 + 1.f;                  // sigma1_sq
        float s2 = s22 + 1.f;                  // sigma2_sq
        float sv = s12 + 1.f;                  // sigma12
        float a = 2.f * sv;
        float b = s1 + s2;                     // >= 2 on valid lanes
        float rb = __builtin_amdgcn_rcpf(b);
        float S0 = a * rb;
        float Sp = (b - a) * rb * rb;          // dS/dC2
        float m12 = fmaf(M1, M2, 1.f);
        float nb = 2.f * m12;
        float N1 = nb * nb;
        float ms = fmaf(M1, M1, fmaf(M2, M2, 2.f));
        float Dv = ms * ms;                    // >= 4 on valid lanes
        float rD = __builtin_amdgcn_rcpf(Dv);
        float B0 = N1 * rD;
        float Bp = (Dv - N1) * rD * rD;        // dB/dC1
        float t0v = S0 * B0, t1v = S0 * Bp, t2v = B0 * Sp;
        acc0 += oma ? t0v : 0.f;               // select blocks NaN from halo lanes
        aC1 += oma ? t1v : 0.f;
        aC2 += oma ? t2v : 0.f;
      }
    }
  }

  // wave reduction (64 lanes), then block partials via tiny LDS
  #pragma unroll
  for (int off = 32; off > 0; off >>= 1) {
    acc0 += __shfl_down(acc0, off);
    aC1 += __shfl_down(aC1, off);
    aC2 += __shfl_down(aC2, off);
    vmin = fminf(vmin, __shfl_down(vmin, off));
    vmax = fmaxf(vmax, __shfl_down(vmax, off));
  }
  if (lane == 0) {
    redbuf[wv][0] = acc0; redbuf[wv][1] = aC1; redbuf[wv][2] = aC2;
    redbuf[wv][3] = vmin; redbuf[wv][4] = vmax;
  }
  __syncthreads();
  if (tid == 0) {
    float t0 = 0.f, t1 = 0.f, t2 = 0.f, mn = 1e30f, mx = -1e30f;
    #pragma unroll
    for (int w2 = 0; w2 < 4; ++w2) {
      t0 += redbuf[w2][0]; t1 += redbuf[w2][1]; t2 += redbuf[w2][2];
      mn = fminf(mn, redbuf[w2][3]); mx = fmaxf(mx, redbuf[w2][4]);
    }
    float* wsF = (float*)ws;
    atomicAdd(&wsF[0], t0);
    atomicAdd(&wsF[1], t1);
    atomicAdd(&wsF[2], t2);
    atomicMin(&ws[3], fkey(mn));
    atomicMax(&ws[4], fkey(mx));
  }
}

__global__ void ssim_final(const unsigned* __restrict__ ws, float* __restrict__ out) {
  const float* wsF = (const float*)ws;
  float mn = funkey(ws[3]);
  float mx = funkey(ws[4]);
  float vr = mx - mn + 1e-5f;
  float c1 = 0.01f * vr; c1 *= c1;
  float c2 = 0.03f * vr; c2 *= c2;
  float mean = (wsF[0] + c1 * wsF[1] + c2 * wsF[2]) * (1.0f / 16777216.0f);
  out[0] = 1.f - mean;
}

extern "C" void kernel_launch(void* const* d_in, const int* in_sizes, int n_in,
                              void* d_out, int out_size, void* d_ws, size_t ws_size,
                              hipStream_t stream) {
  const float* img1 = (const float*)d_in[0];
  const float* img2 = (const float*)d_in[1];
  const float* kern = (const float*)d_in[2];
  unsigned* ws = (unsigned*)d_ws;
  float* out = (float*)d_out;
  (void)in_sizes; (void)n_in; (void)out_size; (void)ws_size;

  hipLaunchKernelGGL(ssim_init, dim3(1), dim3(1), 0, stream, ws);
  hipLaunchKernelGGL(ssim_main, dim3(NBLK), dim3(256), 0, stream,
                     img1, img2, kern, ws);
  hipLaunchKernelGGL(ssim_final, dim3(1), dim3(1), 0, stream, ws, out);
}